// Round 1
// baseline (3787.492 us; speedup 1.0000x reference)
//
#include <hip/hip_runtime.h>
#include <cstdint>
#include <cstddef>
#include <math.h>

#define L_ 1024
#define DK_ 64
#define DV_ 64
#define N_ 64
#define H_ 8
#define B_ 8

// ---------------------------------------------------------------------------
// K1: xm = tril(q_rm @ k^T / 8)  written into d_out's attn region.
// Upper-triangular 64x64 tiles are written as zeros (conv input must be
// exactly where(mask,0,attn_rm)). 64x64 tile per block, 256 threads,
// 4x4 micro-tile per thread.
// ---------------------------------------------------------------------------
__global__ __launch_bounds__(256) void k1_qk_tril(
    const float* __restrict__ qrm, const float* __restrict__ kk,
    float* __restrict__ xm) {
  const int n  = blockIdx.z;
  const int q0 = blockIdx.y * 64;
  const int j0 = blockIdx.x * 64;
  const int t  = threadIdx.x;

  if (j0 > q0) {  // strictly above diagonal: zeros
    const float4 z = make_float4(0.f, 0.f, 0.f, 0.f);
    #pragma unroll
    for (int i = 0; i < 4; ++i) {
      const int row = (t >> 4) + i * 16;
      const int c4  = t & 15;
      float4* p = (float4*)(xm + ((size_t)(n * L_ + q0 + row)) * L_ + j0);
      p[c4] = z;
    }
    return;
  }

  __shared__ float As[64][65];
  __shared__ float Bs[64][65];
  #pragma unroll
  for (int i = 0; i < 4; ++i) {
    const int row = (t >> 4) + i * 16;
    const int c4  = t & 15;
    const float4 a = ((const float4*)(qrm + ((size_t)(n * L_ + q0 + row)) * DK_))[c4];
    const float4 b = ((const float4*)(kk  + ((size_t)(n * L_ + j0 + row)) * DK_))[c4];
    As[row][c4 * 4 + 0] = a.x; As[row][c4 * 4 + 1] = a.y;
    As[row][c4 * 4 + 2] = a.z; As[row][c4 * 4 + 3] = a.w;
    Bs[row][c4 * 4 + 0] = b.x; Bs[row][c4 * 4 + 1] = b.y;
    Bs[row][c4 * 4 + 2] = b.z; Bs[row][c4 * 4 + 3] = b.w;
  }
  __syncthreads();

  const int ty = t >> 4, tx = t & 15;
  float acc[4][4];
  #pragma unroll
  for (int i = 0; i < 4; ++i)
    #pragma unroll
    for (int j = 0; j < 4; ++j) acc[i][j] = 0.f;

  for (int d = 0; d < 64; ++d) {
    float a[4], b[4];
    #pragma unroll
    for (int i = 0; i < 4; ++i) a[i] = As[ty * 4 + i][d];
    #pragma unroll
    for (int j = 0; j < 4; ++j) b[j] = Bs[tx * 4 + j][d];
    #pragma unroll
    for (int i = 0; i < 4; ++i)
      #pragma unroll
      for (int j = 0; j < 4; ++j) acc[i][j] += a[i] * b[j];
  }

  #pragma unroll
  for (int i = 0; i < 4; ++i) {
    const int gq = q0 + ty * 4 + i;
    float* rowp = xm + ((size_t)(n * L_ + gq)) * L_;
    #pragma unroll
    for (int j = 0; j < 4; ++j) {
      const int gj = j0 + tx * 4 + j;
      rowp[gj] = (gj <= gq) ? acc[i][j] * 0.125f : 0.f;
    }
  }
}

// ---------------------------------------------------------------------------
// K2: xs = relu(conv3x3_{H->H}(xm))  (SAME, zero pad), computed only where
// c <= r+1 (covers both fg paths). Block = (b, 4 rows, 64 cols), all 8
// output channels. Input tile 8ch x 6rows x 66cols staged in LDS.
// ---------------------------------------------------------------------------
__global__ __launch_bounds__(256) void k2_conv(
    const float* __restrict__ xm, const float* __restrict__ w,
    float* __restrict__ xs) {
  const int ct = blockIdx.x, rt = blockIdx.y, b = blockIdx.z;
  const int r0 = rt * 4, c0 = ct * 64;
  if (c0 > r0 + 4) return;  // tile entirely outside needed region

  __shared__ float in_s[8][6][68];
  __shared__ float ws[576];
  const int t = threadIdx.x;

  for (int i = t; i < 576; i += 256) ws[i] = w[i];
  for (int e = t; e < 8 * 6 * 66; e += 256) {
    const int hi  = e / 396;
    const int rem = e - hi * 396;
    const int rr  = rem / 66;
    const int cc  = rem - rr * 66;
    const int gr  = r0 - 1 + rr;
    const int gc  = c0 - 1 + cc;
    float v = 0.f;
    if (gr >= 0 && gr < L_ && gc >= 0 && gc < L_)
      v = xm[((size_t)((b * 8 + hi) * L_ + gr)) * L_ + gc];
    in_s[hi][rr][cc] = v;
  }
  __syncthreads();

  const int cc = t & 63;   // output col within tile
  const int rr = t >> 6;   // output row within tile (0..3)
  float acc[8];
  #pragma unroll
  for (int ho = 0; ho < 8; ++ho) acc[ho] = 0.f;

  #pragma unroll
  for (int hi = 0; hi < 8; ++hi) {
    float iv[3][3];
    #pragma unroll
    for (int di = 0; di < 3; ++di)
      #pragma unroll
      for (int dj = 0; dj < 3; ++dj)
        iv[di][dj] = in_s[hi][rr + di][cc + dj];
    #pragma unroll
    for (int ho = 0; ho < 8; ++ho) {
      const float* wp = &ws[(ho * 8 + hi) * 9];
      #pragma unroll
      for (int di = 0; di < 3; ++di)
        #pragma unroll
        for (int dj = 0; dj < 3; ++dj)
          acc[ho] += iv[di][dj] * wp[di * 3 + dj];
    }
  }

  const int gr = r0 + rr, gc = c0 + cc;
  #pragma unroll
  for (int ho = 0; ho < 8; ++ho)
    xs[((size_t)((b * 8 + ho) * L_ + gr)) * L_ + gc] = fmaxf(acc[ho], 0.f);
}

// ---------------------------------------------------------------------------
// K3: one block per (n, q-row). Recompute s_qk = q.k/8, mix with rm (read
// from attn region, then overwritten), xs (shifted), attn_pre; softmax;
// write attn row; PV matvec -> out row.
// ---------------------------------------------------------------------------
__global__ __launch_bounds__(256) void k3_final(
    const float* __restrict__ q, const float* __restrict__ kk,
    const float* __restrict__ v, const float* __restrict__ pre,
    const int* __restrict__ fgp, const float* __restrict__ xs,
    float* __restrict__ attn, float* __restrict__ out) {
  const int qrow = blockIdx.x;
  const int n    = blockIdx.y;
  const int t    = threadIdx.x;
  const int fg   = *fgp;

  __shared__ float qv[64];
  __shared__ float sbuf[L_];
  __shared__ float red[16];
  __shared__ float pvred[256];

  if (t < 64) qv[t] = q[((size_t)(n * L_ + qrow)) * DK_ + t];
  __syncthreads();

  const float* kbase  = kk + (size_t)n * L_ * DK_;
  const float* prerow = pre + ((size_t)(n * L_ + qrow)) * L_;
  float* arow = attn + ((size_t)(n * L_ + qrow)) * L_;

  for (int j = t; j < L_; j += 256) {
    float sval = -INFINITY;
    if (j <= qrow) {
      float dot = 0.f;
      const float4* kr = (const float4*)(kbase + (size_t)j * DK_);
      #pragma unroll
      for (int d4 = 0; d4 < 16; ++d4) {
        const float4 kx = kr[d4];
        dot += qv[d4 * 4 + 0] * kx.x + qv[d4 * 4 + 1] * kx.y +
               qv[d4 * 4 + 2] * kx.z + qv[d4 * 4 + 3] * kx.w;
      }
      const float s_qk = dot * 0.125f;
      const float rm = arow[j];
      float cnn;
      if (fg == 1) {
        cnn = (qrow == 0 || j == 0)
                  ? rm
                  : xs[((size_t)(n * L_ + qrow - 1)) * L_ + (j - 1)];
      } else {
        cnn = (qrow == 0) ? rm
                          : xs[((size_t)(n * L_ + qrow - 1)) * L_ + j];
      }
      const float mixed = cnn * 0.1f + rm * 0.9f;       // C_MIX
      const float a2    = mixed * 0.4f + s_qk * 0.6f;   // B_MIX
      sval = prerow[j] * 0.1f + a2 * 0.9f;              // A_MIX
    }
    sbuf[j] = sval;
  }
  __syncthreads();

  // row max
  float m = -INFINITY;
  for (int j = t; j < L_; j += 256) m = fmaxf(m, sbuf[j]);
  #pragma unroll
  for (int off = 32; off > 0; off >>= 1) m = fmaxf(m, __shfl_down(m, off));
  const int wid = t >> 6, lane = t & 63;
  if (lane == 0) red[wid] = m;
  __syncthreads();
  if (t == 0)
    red[8] = fmaxf(fmaxf(red[0], red[1]), fmaxf(red[2], red[3]));
  __syncthreads();
  const float rowmax = red[8];

  // exp + sum
  float ssum = 0.f;
  for (int j = t; j < L_; j += 256) {
    const float e = (j <= qrow) ? __expf(sbuf[j] - rowmax) : 0.f;
    sbuf[j] = e;
    ssum += e;
  }
  #pragma unroll
  for (int off = 32; off > 0; off >>= 1) ssum += __shfl_down(ssum, off);
  if (lane == 0) red[wid] = ssum;
  __syncthreads();
  if (t == 0) red[8] = red[0] + red[1] + red[2] + red[3];
  __syncthreads();
  const float inv = 1.f / red[8];

  // normalize, write attn row (zeros above diagonal)
  for (int j = t; j < L_; j += 256) {
    const float p = sbuf[j] * inv;
    sbuf[j] = p;
    arow[j] = p;
  }
  __syncthreads();

  // PV: out[q,d] = sum_j p[j] * v[j,d]
  const int d = t & 63, g = t >> 6;
  const float* vb = v + (size_t)n * L_ * DV_;
  float accd = 0.f;
  for (int j = g; j <= qrow; j += 4)
    accd += sbuf[j] * vb[(size_t)j * DV_ + d];
  pvred[t] = accd;
  __syncthreads();
  if (g == 0)
    out[((size_t)(n * L_ + qrow)) * DV_ + d] =
        pvred[d] + pvred[64 + d] + pvred[128 + d] + pvred[192 + d];
}

// ---------------------------------------------------------------------------
extern "C" void kernel_launch(void* const* d_in, const int* in_sizes, int n_in,
                              void* d_out, int out_size, void* d_ws,
                              size_t ws_size, hipStream_t stream) {
  const float* q   = (const float*)d_in[0];
  const float* kk  = (const float*)d_in[1];
  const float* v   = (const float*)d_in[2];
  const float* qrm = (const float*)d_in[3];
  const float* pre = (const float*)d_in[4];
  const float* cw  = (const float*)d_in[5];
  // d_in[6] = mask (deterministic causal mask, computed analytically)
  const int* fg = (const int*)d_in[7];

  float* out  = (float*)d_out;
  float* attn = out + (size_t)N_ * L_ * DV_;  // second output, also xm staging
  float* xs   = (float*)d_ws;                 // conv output, N*L*L f32

  k1_qk_tril<<<dim3(16, 16, 64), 256, 0, stream>>>(qrm, kk, attn);
  k2_conv<<<dim3(16, 256, 8), 256, 0, stream>>>(attn, cw, xs);
  k3_final<<<dim3(1024, 64), 256, 0, stream>>>(q, kk, v, pre, fg, xs, attn, out);
}

// Round 2
// 1823.638 us; speedup vs baseline: 2.0769x; 2.0769x over previous
//
#include <hip/hip_runtime.h>
#include <cstdint>
#include <cstddef>
#include <math.h>

#define L_ 1024
#define DK_ 64
#define DV_ 64
#define N_ 64
#define H_ 8
#define B_ 8

// readlane broadcast: all lanes get lane `src`'s value of v. src is uniform.
__device__ __forceinline__ float bcast(float v, int src) {
  return __int_as_float(__builtin_amdgcn_readlane(__float_as_int(v), src));
}

// ---------------------------------------------------------------------------
// K1: xm = tril(q_rm @ k^T / 8) written into d_out's attn region.
// Upper-triangular 64x64 tiles written as zeros (conv input must be exactly
// where(mask,0,attn_rm)). 64x64 tile per block, 256 threads, 4x4 microtile.
// ---------------------------------------------------------------------------
__global__ __launch_bounds__(256) void k1_qk_tril(
    const float* __restrict__ qrm, const float* __restrict__ kk,
    float* __restrict__ xm) {
  const int n  = blockIdx.z;
  const int q0 = blockIdx.y * 64;
  const int j0 = blockIdx.x * 64;
  const int t  = threadIdx.x;

  if (j0 > q0) {  // strictly above diagonal: zeros
    const float4 z = make_float4(0.f, 0.f, 0.f, 0.f);
    #pragma unroll
    for (int i = 0; i < 4; ++i) {
      const int row = (t >> 4) + i * 16;
      const int c4  = t & 15;
      float4* p = (float4*)(xm + ((size_t)(n * L_ + q0 + row)) * L_ + j0);
      p[c4] = z;
    }
    return;
  }

  __shared__ float As[64][65];
  __shared__ float Bs[64][65];
  #pragma unroll
  for (int i = 0; i < 4; ++i) {
    const int row = (t >> 4) + i * 16;
    const int c4  = t & 15;
    const float4 a = ((const float4*)(qrm + ((size_t)(n * L_ + q0 + row)) * DK_))[c4];
    const float4 b = ((const float4*)(kk  + ((size_t)(n * L_ + j0 + row)) * DK_))[c4];
    As[row][c4 * 4 + 0] = a.x; As[row][c4 * 4 + 1] = a.y;
    As[row][c4 * 4 + 2] = a.z; As[row][c4 * 4 + 3] = a.w;
    Bs[row][c4 * 4 + 0] = b.x; Bs[row][c4 * 4 + 1] = b.y;
    Bs[row][c4 * 4 + 2] = b.z; Bs[row][c4 * 4 + 3] = b.w;
  }
  __syncthreads();

  const int ty = t >> 4, tx = t & 15;
  float acc[4][4];
  #pragma unroll
  for (int i = 0; i < 4; ++i)
    #pragma unroll
    for (int j = 0; j < 4; ++j) acc[i][j] = 0.f;

  for (int d = 0; d < 64; ++d) {
    float a[4], b[4];
    #pragma unroll
    for (int i = 0; i < 4; ++i) a[i] = As[ty * 4 + i][d];
    #pragma unroll
    for (int j = 0; j < 4; ++j) b[j] = Bs[tx * 4 + j][d];
    #pragma unroll
    for (int i = 0; i < 4; ++i)
      #pragma unroll
      for (int j = 0; j < 4; ++j) acc[i][j] += a[i] * b[j];
  }

  #pragma unroll
  for (int i = 0; i < 4; ++i) {
    const int gq = q0 + ty * 4 + i;
    float* rowp = xm + ((size_t)(n * L_ + gq)) * L_;
    #pragma unroll
    for (int j = 0; j < 4; ++j) {
      const int gj = j0 + tx * 4 + j;
      rowp[gj] = (gj <= gq) ? acc[i][j] * 0.125f : 0.f;
    }
  }
}

// ---------------------------------------------------------------------------
// K2: xs = relu(conv3x3_{H->H}(xm)) (SAME, zero pad), only where c <= r+4
// per 4-row tile (covers both fg shift variants).
// ---------------------------------------------------------------------------
__global__ __launch_bounds__(256) void k2_conv(
    const float* __restrict__ xm, const float* __restrict__ w,
    float* __restrict__ xs) {
  const int ct = blockIdx.x, rt = blockIdx.y, b = blockIdx.z;
  const int r0 = rt * 4, c0 = ct * 64;
  if (c0 > r0 + 4) return;  // tile entirely outside needed region

  __shared__ float in_s[8][6][68];
  __shared__ float ws[576];
  const int t = threadIdx.x;

  for (int i = t; i < 576; i += 256) ws[i] = w[i];
  for (int e = t; e < 8 * 6 * 66; e += 256) {
    const int hi  = e / 396;
    const int rem = e - hi * 396;
    const int rr  = rem / 66;
    const int cc  = rem - rr * 66;
    const int gr  = r0 - 1 + rr;
    const int gc  = c0 - 1 + cc;
    float v = 0.f;
    if (gr >= 0 && gr < L_ && gc >= 0 && gc < L_)
      v = xm[((size_t)((b * 8 + hi) * L_ + gr)) * L_ + gc];
    in_s[hi][rr][cc] = v;
  }
  __syncthreads();

  const int cc = t & 63;
  const int rr = t >> 6;
  float acc[8];
  #pragma unroll
  for (int ho = 0; ho < 8; ++ho) acc[ho] = 0.f;

  #pragma unroll
  for (int hi = 0; hi < 8; ++hi) {
    float iv[3][3];
    #pragma unroll
    for (int di = 0; di < 3; ++di)
      #pragma unroll
      for (int dj = 0; dj < 3; ++dj)
        iv[di][dj] = in_s[hi][rr + di][cc + dj];
    #pragma unroll
    for (int ho = 0; ho < 8; ++ho) {
      const float* wp = &ws[(ho * 8 + hi) * 9];
      #pragma unroll
      for (int di = 0; di < 3; ++di)
        #pragma unroll
        for (int dj = 0; dj < 3; ++dj)
          acc[ho] += iv[di][dj] * wp[di * 3 + dj];
    }
  }

  const int gr = r0 + rr, gc = c0 + cc;
  #pragma unroll
  for (int ho = 0; ho < 8; ++ho)
    xs[((size_t)((b * 8 + ho) * L_ + gr)) * L_ + gc] = fmaxf(acc[ho], 0.f);
}

// ---------------------------------------------------------------------------
// K3: fused scores + online softmax + attn write + PV.
// Block = 16 q-rows of one n. 256 threads = 4 waves; wave g owns rows
// {g, g+4, g+8, g+12}; lane = column within a 64-wide j-tile.
// Phase A: per j-tile, stage k^T in LDS, compute mixed scores S, write raw S
//          into attn (overwriting rm), track online (m,l) per row in-wave.
// Phase C: re-read S (L2-hot), p = exp(S-m)/l, write attn, accumulate PV via
//          readlane broadcasts against coalesced v loads. No barriers.
// ---------------------------------------------------------------------------
__global__ __launch_bounds__(256) void k3_fused(
    const float* __restrict__ q, const float* __restrict__ kk,
    const float* __restrict__ v, const float* __restrict__ pre,
    const int* __restrict__ fgp, const float* __restrict__ xs,
    float* attn, float* __restrict__ out) {
  const int n    = blockIdx.y;
  const int q0   = blockIdx.x * 16;
  const int t    = threadIdx.x;
  const int lane = t & 63;
  const int g    = t >> 6;  // wave id 0..3
  const int fg   = *fgp;

  __shared__ float kt[64][65];  // k^T tile, padded: kt[d][c] bank (d+c)%32

  // q held in registers: lane c holds q[n][q0+r_i][c]
  const float* qb = q + ((size_t)(n * L_ + q0)) * DK_;
  float qreg[4];
  #pragma unroll
  for (int i = 0; i < 4; ++i) qreg[i] = qb[(size_t)(g + i * 4) * DK_ + lane];

  float m[4], l[4];
  #pragma unroll
  for (int i = 0; i < 4; ++i) { m[i] = -INFINITY; l[i] = 0.f; }

  const int ntiles = (q0 >> 6) + 1;
  const float* kbase = kk + (size_t)n * L_ * DK_;

  // ---------------- Phase A: scores + online (m, l) ----------------
  for (int tile = 0; tile < ntiles; ++tile) {
    const int j0 = tile * 64;
    __syncthreads();
    #pragma unroll
    for (int i = 0; i < 4; ++i) {
      const int row = (t >> 4) + i * 16;
      const int c4  = t & 15;
      const float4 kx =
          *(const float4*)(kbase + (size_t)(j0 + row) * DK_ + c4 * 4);
      kt[c4 * 4 + 0][row] = kx.x;
      kt[c4 * 4 + 1][row] = kx.y;
      kt[c4 * 4 + 2][row] = kx.z;
      kt[c4 * 4 + 3][row] = kx.w;
    }
    __syncthreads();

    float dot[4] = {0.f, 0.f, 0.f, 0.f};
    #pragma unroll
    for (int d = 0; d < 64; ++d) {
      const float kd = kt[d][lane];
      #pragma unroll
      for (int i = 0; i < 4; ++i) dot[i] += bcast(qreg[i], d) * kd;
    }

    const int j = j0 + lane;
    #pragma unroll
    for (int i = 0; i < 4; ++i) {
      const int r = q0 + g + i * 4;
      float s = -INFINITY;
      if (j <= r) {
        const float s_qk = dot[i] * 0.125f;
        const float rm   = attn[((size_t)(n * L_ + r)) * L_ + j];
        float cnn;
        if (fg == 1)
          cnn = (r == 0 || j == 0)
                    ? rm
                    : xs[((size_t)(n * L_ + r - 1)) * L_ + (j - 1)];
        else
          cnn = (r == 0) ? rm : xs[((size_t)(n * L_ + r - 1)) * L_ + j];
        const float mixed = cnn * 0.1f + rm * 0.9f;    // C_MIX
        const float a2    = mixed * 0.4f + s_qk * 0.6f; // B_MIX
        s = pre[((size_t)(n * L_ + r)) * L_ + j] * 0.1f + a2 * 0.9f; // A_MIX
      }
      attn[((size_t)(n * L_ + r)) * L_ + j] = s;  // raw S (or -inf)

      float mt = s;
      #pragma unroll
      for (int o = 32; o > 0; o >>= 1) mt = fmaxf(mt, __shfl_xor(mt, o));
      const float mn = fmaxf(m[i], mt);
      float e = __expf(s - mn);  // s=-inf -> 0
      float es = e;
      #pragma unroll
      for (int o = 32; o > 0; o >>= 1) es += __shfl_xor(es, o);
      l[i] = l[i] * __expf(m[i] - mn) + es;
      m[i] = mn;
    }
  }

  __syncthreads();  // drain raw-S writes before re-read

  // ---------------- Phase C: normalize + attn write + PV ----------------
  float invl[4];
  #pragma unroll
  for (int i = 0; i < 4; ++i) invl[i] = 1.f / l[i];

  float acc[4] = {0.f, 0.f, 0.f, 0.f};
  const float* vb = v + (size_t)n * L_ * DV_;

  for (int tile = 0; tile < ntiles; ++tile) {
    const int j0 = tile * 64;
    const int j  = j0 + lane;
    float p[4];
    #pragma unroll
    for (int i = 0; i < 4; ++i) {
      const int r = q0 + g + i * 4;
      const float s = attn[((size_t)(n * L_ + r)) * L_ + j];
      const float pv = __expf(s - m[i]) * invl[i];
      p[i] = pv;
      attn[((size_t)(n * L_ + r)) * L_ + j] = pv;
    }
    #pragma unroll
    for (int c = 0; c < 64; ++c) {
      const float vv = vb[(size_t)(j0 + c) * DV_ + lane];
      #pragma unroll
      for (int i = 0; i < 4; ++i) acc[i] += bcast(p[i], c) * vv;
    }
  }

  #pragma unroll
  for (int i = 0; i < 4; ++i) {
    const int r = q0 + g + i * 4;
    out[((size_t)(n * L_ + r)) * DV_ + lane] = acc[i];
  }
}

// ---------------------------------------------------------------------------
extern "C" void kernel_launch(void* const* d_in, const int* in_sizes, int n_in,
                              void* d_out, int out_size, void* d_ws,
                              size_t ws_size, hipStream_t stream) {
  const float* q   = (const float*)d_in[0];
  const float* kk  = (const float*)d_in[1];
  const float* v   = (const float*)d_in[2];
  const float* qrm = (const float*)d_in[3];
  const float* pre = (const float*)d_in[4];
  const float* cw  = (const float*)d_in[5];
  // d_in[6] = mask (deterministic causal, computed analytically)
  const int* fg = (const int*)d_in[7];

  float* out  = (float*)d_out;
  float* attn = out + (size_t)N_ * L_ * DV_;  // second output; also rm/S staging
  float* xs   = (float*)d_ws;                 // conv output, N*L*L f32

  k1_qk_tril<<<dim3(16, 16, 64), 256, 0, stream>>>(qrm, kk, attn);
  k2_conv<<<dim3(16, 256, 8), 256, 0, stream>>>(attn, cw, xs);
  k3_fused<<<dim3(64, 64), 256, 0, stream>>>(q, kk, v, pre, fg, xs, attn, out);
}